// Round 3
// baseline (194.003 us; speedup 1.0000x reference)
//
#include <hip/hip_runtime.h>
#include <math.h>

// Problem constants
#define KS    11
#define H     512
#define W     512
#define OH    502
#define OW    502
#define NPLANES 48
#define TOTAL_OUT (NPLANES * OH * OW)   // 12,096,192

// Tiling: 2 wide tiles per row-band. Tile 0: out cols 0..245 (in 0..255)
//         Tile 1: out cols 246..501 (in 246..511)
#define TH      8                 // output rows per block
#define IROWS   (TH + KS - 1)     // 18 input rows per block
#define LVW     268               // EVEN row stride (words): rows 16B-aligned -> ds_read_b128
#define NTHREADS 256

__global__ void zero_out_kernel(float* out) { out[0] = 0.0f; }

__global__ __launch_bounds__(NTHREADS) void ssim_kernel(
    const float* __restrict__ x,
    const float* __restrict__ y,
    const float* __restrict__ win,
    float* __restrict__ out)
{
    // Chunked intermediates: chunk A uses planes 0,1 (mu_x, mu_y);
    // chunk B uses planes 0,1,2 (xx, yy, xy). 3*8*268*4 = 25.7 KB -> 6 blocks/CU.
    __shared__ float v[3][TH][LVW];
    __shared__ float w1s[KS];
    __shared__ float wsum[NTHREADS / 64];

    const int t     = threadIdx.x;
    const int bx    = blockIdx.x;              // 0 or 1
    const int x0    = bx * 246;                // col base (input & output)
    const int gy0   = blockIdx.y * TH;         // output row base
    const int plane = blockIdx.z;
    const int IWx   = bx ? 266 : 256;          // input cols this tile
    const int TWx   = bx ? 256 : 246;          // output cols this tile

    const float* __restrict__ xp = x + (size_t)plane * (H * W);
    const float* __restrict__ yp = y + (size_t)plane * (H * W);

    // Separable taps: window = outer(g,g) => g[i] = sqrt(win[i][i])
    if (t < KS) w1s[t] = sqrtf(win[t * KS + t]);
    __syncthreads();

    float w[KS];
#pragma unroll
    for (int k = 0; k < KS; k++) w[k] = w1s[k];

    const int r  = t & 7;            // stage-2 row within tile
    const int c0 = (t >> 3) << 3;    // stage-2 run start col (mult of 8 -> 16B aligned)

    // ================= CHUNK A: mu_x, mu_y =================
    // Stage 1a: vertical conv of x, y (global -> regs -> LDS)
    for (int cc = t; cc < IWx; cc += NTHREADS) {
        const int gx = x0 + cc;
        float a0[TH], a1[TH];
#pragma unroll
        for (int rr = 0; rr < TH; rr++) { a0[rr] = 0.f; a1[rr] = 0.f; }
#pragma unroll
        for (int j = 0; j < IROWS; j++) {
            const int gy = gy0 + j;
            float xv = 0.f, yv = 0.f;
            if (gy < H) {
                xv = xp[gy * W + gx];
                yv = yp[gy * W + gx];
            }
#pragma unroll
            for (int rr = 0; rr < TH; rr++) {
                if (j - rr >= 0 && j - rr < KS) {   // constant-folds after unroll
                    const float wk = w[j - rr];
                    a0[rr] += wk * xv;
                    a1[rr] += wk * yv;
                }
            }
        }
#pragma unroll
        for (int rr = 0; rr < TH; rr++) {
            v[0][rr][cc] = a0[rr];
            v[1][rr][cc] = a1[rr];
        }
    }
    __syncthreads();

    // Stage 2a: horizontal conv -> mu per pixel (kept in regs across chunk B)
    float mux[TH], muy[TH];
    {
        float vs[IROWS];
#pragma unroll
        for (int j = 0; j < IROWS; j++) vs[j] = v[0][r][c0 + j];
#pragma unroll
        for (int p = 0; p < TH; p++) {
            float m = 0.f;
#pragma unroll
            for (int k = 0; k < KS; k++) m += w[k] * vs[p + k];
            mux[p] = m;
        }
#pragma unroll
        for (int j = 0; j < IROWS; j++) vs[j] = v[1][r][c0 + j];
#pragma unroll
        for (int p = 0; p < TH; p++) {
            float m = 0.f;
#pragma unroll
            for (int k = 0; k < KS; k++) m += w[k] * vs[p + k];
            muy[p] = m;
        }
    }
    __syncthreads();   // before chunk B overwrites v

    // ================= CHUNK B: xx, yy, xy =================
    // Stage 1b: vertical conv of x*x, y*y, x*y (re-read x,y: L2-resident)
    for (int cc = t; cc < IWx; cc += NTHREADS) {
        const int gx = x0 + cc;
        float a2[TH], a3[TH], a4[TH];
#pragma unroll
        for (int rr = 0; rr < TH; rr++) { a2[rr] = 0.f; a3[rr] = 0.f; a4[rr] = 0.f; }
#pragma unroll
        for (int j = 0; j < IROWS; j++) {
            const int gy = gy0 + j;
            float xv = 0.f, yv = 0.f;
            if (gy < H) {
                xv = xp[gy * W + gx];
                yv = yp[gy * W + gx];
            }
            const float xx = xv * xv;
            const float yy = yv * yv;
            const float xy = xv * yv;
#pragma unroll
            for (int rr = 0; rr < TH; rr++) {
                if (j - rr >= 0 && j - rr < KS) {
                    const float wk = w[j - rr];
                    a2[rr] += wk * xx;
                    a3[rr] += wk * yy;
                    a4[rr] += wk * xy;
                }
            }
        }
#pragma unroll
        for (int rr = 0; rr < TH; rr++) {
            v[0][rr][cc] = a2[rr];
            v[1][rr][cc] = a3[rr];
            v[2][rr][cc] = a4[rr];
        }
    }
    __syncthreads();

    // Stage 2b: horizontal conv of second moments + SSIM
    float mxx[TH], myy[TH], mxy[TH];
    {
        float vs[IROWS];
#pragma unroll
        for (int j = 0; j < IROWS; j++) vs[j] = v[0][r][c0 + j];
#pragma unroll
        for (int p = 0; p < TH; p++) {
            float m = 0.f;
#pragma unroll
            for (int k = 0; k < KS; k++) m += w[k] * vs[p + k];
            mxx[p] = m;
        }
#pragma unroll
        for (int j = 0; j < IROWS; j++) vs[j] = v[1][r][c0 + j];
#pragma unroll
        for (int p = 0; p < TH; p++) {
            float m = 0.f;
#pragma unroll
            for (int k = 0; k < KS; k++) m += w[k] * vs[p + k];
            myy[p] = m;
        }
#pragma unroll
        for (int j = 0; j < IROWS; j++) vs[j] = v[2][r][c0 + j];
#pragma unroll
        for (int p = 0; p < TH; p++) {
            float m = 0.f;
#pragma unroll
            for (int k = 0; k < KS; k++) m += w[k] * vs[p + k];
            mxy[p] = m;
        }
    }

    const float c1 = 1e-4f;   // (0.01)^2
    const float c2 = 9e-4f;   // (0.03)^2
    const int grow = gy0 + r;
    float acc = 0.f;
#pragma unroll
    for (int p = 0; p < TH; p++) {
        if ((c0 + p) < TWx && grow < OH) {
            const float a = mux[p], b = muy[p];
            const float sxx = mxx[p] - a * a;
            const float syy = myy[p] - b * b;
            const float sxy = mxy[p] - a * b;
            const float num = (2.f * sxy + c2) * (2.f * a * b + c1);
            const float den = (sxx + syy + c2) * (a * a + b * b + c1);
            acc += num * __builtin_amdgcn_rcpf(den);
        }
    }

    // ---- Reduction: wave shuffle -> cross-wave LDS -> one atomic/block ----
#pragma unroll
    for (int off = 32; off > 0; off >>= 1)
        acc += __shfl_down(acc, off, 64);

    if ((t & 63) == 0) wsum[t >> 6] = acc;
    __syncthreads();
    if (t == 0) {
        float s = 0.f;
#pragma unroll
        for (int i = 0; i < NTHREADS / 64; i++) s += wsum[i];
        atomicAdd(out, s * (1.0f / (float)TOTAL_OUT));
    }
}

extern "C" void kernel_launch(void* const* d_in, const int* in_sizes, int n_in,
                              void* d_out, int out_size, void* d_ws, size_t ws_size,
                              hipStream_t stream)
{
    const float* x   = (const float*)d_in[0];
    const float* y   = (const float*)d_in[1];
    const float* win = (const float*)d_in[2];
    float* out = (float*)d_out;

    zero_out_kernel<<<1, 1, 0, stream>>>(out);

    dim3 grid(2, (OH + TH - 1) / TH, NPLANES);   // (2, 63, 48) = 6048 blocks
    ssim_kernel<<<grid, NTHREADS, 0, stream>>>(x, y, win, out);
}